// Round 4
// baseline (2051.699 us; speedup 1.0000x reference)
//
#include <hip/hip_runtime.h>

#define NSTEPS 8
#define DT (1.0f / NSTEPS)

typedef __bf16 bfv8 __attribute__((ext_vector_type(8)));
typedef float f32x4 __attribute__((ext_vector_type(4)));

__device__ __forceinline__ float fast_tanh(float x) {
  float e = __expf(2.f * x);
  return 1.f - 2.f * __builtin_amdgcn_rcpf(e + 1.f);
}

__device__ __forceinline__ f32x4 splat4(float v) {
  f32x4 r; r[0] = v; r[1] = v; r[2] = v; r[3] = v; return r;
}

// ---------------------------------------------------------------------------
// Packed weight layouts (bf16), fragment-major for coalesced B-loads:
//  W1P[kq][512][8]  kq<8  : W1P[kq*4096+col*8+e] = W1[(kq*8+e)*512+col]
//  W2P[kc][512][8]  kc<64 : = W2[(kc*8+e)*512+col]
//  GtP[kc][512][8]  kc<64 : = G[j=col, k=kc*8+e],  G[j,k]=W2[j,k]*sum_i W1[i,j]W3[k,i]
//  W3P[kc][64][8]   kc<64 : = W3[(kc*8+e)*64+m]
// ---------------------------------------------------------------------------
__global__ __launch_bounds__(256) void pre_kernel(
    const float* __restrict__ W1, const float* __restrict__ W2,
    const float* __restrict__ W3, __bf16* __restrict__ W1P,
    __bf16* __restrict__ W2P, __bf16* __restrict__ GtP,
    __bf16* __restrict__ W3P) {
  int t = blockIdx.x * 256 + threadIdx.x;  // 73728 frags total
  if (t < 4096) {
    int kq = t >> 9, col = t & 511;
    bfv8 o;
#pragma unroll
    for (int e = 0; e < 8; ++e) o[e] = (__bf16)W1[(kq * 8 + e) * 512 + col];
    *(bfv8*)(W1P + t * 8) = o;
  } else if (t < 36864) {
    int g = t - 4096;
    int kc = g >> 9, col = g & 511;
    bfv8 o;
#pragma unroll
    for (int e = 0; e < 8; ++e) o[e] = (__bf16)W2[(kc * 8 + e) * 512 + col];
    *(bfv8*)(W2P + g * 8) = o;
  } else if (t < 69632) {
    int g = t - 36864;
    int kc = g >> 9, j = g & 511;
    float w1c[64];
#pragma unroll
    for (int m = 0; m < 64; ++m) w1c[m] = W1[m * 512 + j];
    bfv8 o;
#pragma unroll
    for (int e = 0; e < 8; ++e) {
      int k = kc * 8 + e;
      float s = 0.f;
#pragma unroll
      for (int m = 0; m < 64; ++m) s = fmaf(w1c[m], W3[k * 64 + m], s);
      o[e] = (__bf16)(s * W2[j * 512 + k]);
    }
    *(bfv8*)(GtP + g * 8) = o;
  } else if (t < 73728) {
    int g = t - 69632;
    int kc = g >> 6, m = g & 63;
    bfv8 o;
#pragma unroll
    for (int e = 0; e < 8; ++e) o[e] = (__bf16)W3[(kc * 8 + e) * 64 + m];
    *(bfv8*)(W3P + g * 8) = o;
  }
}

// Prefetch one phase-C chunk (8 B-frags from global, 8 A-frags from LDS).
__device__ __forceinline__ void pref_chunk(
    int id, int lr, int lq, const __bf16* __restrict__ GtP,
    const __bf16* __restrict__ W3P, const char* vs_c, const char* h2_c,
    bfv8 (&Ae)[8], bfv8 (&Be)[8]) {
  const bool isTR = id < 64;
  const int tl = (isTR ? id : id - 64) >> 1;
  const int hf = id & 1;
  const char* ab = isTR ? vs_c : h2_c;
  const __bf16* bb = isTR ? GtP : W3P;
  const int ks = isTR ? 4096 : 512;
  const __bf16* bp = bb + lq * ks + (tl * 16 + lr) * 8 + hf * 32 * ks;
#pragma unroll
  for (int c = 0; c < 8; ++c) {
    Be[c] = *(const bfv8*)(bp + c * 4 * ks);
    Ae[c] = *(const bfv8*)(ab + lr * 1024 +
                           ((((hf * 8 + c) * 64) + lq * 16) ^ ((lr & 7) << 4)));
  }
}

// ---------------------------------------------------------------------------
// Persistent integrator: 32 blocks x 16 rows, 8 waves.
// MFMA 16x16x32 bf16 (m89 mapping): A row=lane&15,k=(lane>>4)*8+i;
// B col=lane&15,same k; D col=lane&15,row=(lane>>4)*4+reg.
// Phases per eval: A[combine(reg)+L1] bar B[L2] bar C[TR+L3, 9 chunks/wave] bar
// ---------------------------------------------------------------------------
__global__ __launch_bounds__(512, 2) void cnf_kernel(
    const float* __restrict__ x, const float* __restrict__ W1,
    const float* __restrict__ b1, const float* __restrict__ b2,
    const float* __restrict__ b3, const __bf16* __restrict__ W1P,
    const __bf16* __restrict__ W2P, const __bf16* __restrict__ GtP,
    const __bf16* __restrict__ W3P, float* __restrict__ out) {
  __shared__ __bf16 h1s[16 * 512];  // row-major, byte ^= (row&7)<<4 swizzle
  __shared__ __bf16 h2s[16 * 512];
  __shared__ __bf16 vs[16 * 512];
  __shared__ float kcur[16 * 64];
  __shared__ float trbuf[16];

  const int tid = threadIdx.x;
  const int lane = tid & 63;
  const int w = tid >> 6;
  const int lr = lane & 15;
  const int lq = lane >> 4;
  const int rowbase = blockIdx.x * 16;
  const char* h1c = (const char*)h1s;
  const char* h2c = (const char*)h2s;
  const char* vsc = (const char*)vs;

  // hoisted per-lane constants
  float b1c[4], w1tc[4], b2c[4], b3c[4];
#pragma unroll
  for (int n = 0; n < 4; ++n) {
    const int col = w * 64 + n * 16 + lr;
    b1c[n] = b1[col];
    w1tc[n] = W1[64 * 512 + col];
    b2c[n] = b2[col];
    b3c[n] = b3[n * 16 + lr];
  }

  // RK4 state in registers (replicated per wave): row lr, k=lq*8+e (+32)
  float xb0[8], xb1[8], ka0[8], ka1[8];
  {
    const float* xr = x + (rowbase + lr) * 64 + lq * 8;
#pragma unroll
    for (int e = 0; e < 8; ++e) {
      xb0[e] = xr[e]; xb1[e] = xr[32 + e]; ka0[e] = 0.f; ka1[e] = 0.f;
    }
  }
  float ldv = 0.f, ldacc = 0.f;  // wave 7 lanes 0..15

#pragma unroll 1
  for (int ev = 0; ev <= 4 * NSTEPS; ++ev) {
    const int g = ev & 3;
    bfv8 a0, a1;
    // ---------------- phase A: combine (registers) ----------------
    if (ev == 0) {
#pragma unroll
      for (int e = 0; e < 8; ++e) { a0[e] = (__bf16)xb0[e]; a1[e] = (__bf16)xb1[e]; }
      if (w == 7 && lq == 0) trbuf[lr] = 0.f;
    } else {
      const int gp = (ev - 1) & 3;
      f32x4 q0 = *(const f32x4*)&kcur[lr * 64 + lq * 8];
      f32x4 q1 = *(const f32x4*)&kcur[lr * 64 + lq * 8 + 4];
      f32x4 q2 = *(const f32x4*)&kcur[lr * 64 + 32 + lq * 8];
      f32x4 q3 = *(const f32x4*)&kcur[lr * 64 + 32 + lq * 8 + 4];
      float kc0[8], kc1[8];
#pragma unroll
      for (int e = 0; e < 4; ++e) { kc0[e] = q0[e]; kc0[e + 4] = q1[e]; kc1[e] = q2[e]; kc1[e + 4] = q3[e]; }
      if (gp < 3) {
        const float wg = (gp == 0) ? 1.f : 2.f;
        const float cn = (gp == 2) ? DT : 0.5f * DT;
#pragma unroll
        for (int e = 0; e < 8; ++e) {
          ka0[e] += wg * kc0[e]; ka1[e] += wg * kc1[e];
          a0[e] = (__bf16)(xb0[e] + cn * kc0[e]);
          a1[e] = (__bf16)(xb1[e] + cn * kc1[e]);
        }
      } else {
#pragma unroll
        for (int e = 0; e < 8; ++e) {
          xb0[e] += (DT / 6.f) * (ka0[e] + kc0[e]);
          xb1[e] += (DT / 6.f) * (ka1[e] + kc1[e]);
          ka0[e] = 0.f; ka1[e] = 0.f;
          a0[e] = (__bf16)xb0[e]; a1[e] = (__bf16)xb1[e];
        }
      }
      if (w == 7 && lq == 0) {
        const float tv = trbuf[lr];
        trbuf[lr] = 0.f;
        if (gp < 3) ldacc += ((gp == 0) ? 1.f : 2.f) * tv;
        else { ldv -= (DT / 6.f) * (ldacc + tv); ldacc = 0.f; }
      }
    }
    if (ev == 4 * NSTEPS) break;

    // ---------------- phase A: L1 ----------------
    const float t = (ev >> 2) * DT + ((g == 0) ? 0.f : (g == 3) ? DT : 0.5f * DT);
#pragma unroll
    for (int n = 0; n < 4; ++n) {
      const int col = w * 64 + n * 16 + lr;
      bfv8 B0 = *(const bfv8*)(W1P + lq * 4096 + col * 8);
      bfv8 B1 = *(const bfv8*)(W1P + (lq + 4) * 4096 + col * 8);
      f32x4 C = splat4(b1c[n] + t * w1tc[n]);
      C = __builtin_amdgcn_mfma_f32_16x16x32_bf16(a0, B0, C, 0, 0, 0);
      C = __builtin_amdgcn_mfma_f32_16x16x32_bf16(a1, B1, C, 0, 0, 0);
#pragma unroll
      for (int r = 0; r < 4; ++r) {
        const int row = lq * 4 + r;
        *(__bf16*)((char*)h1s + row * 1024 + ((col * 2) ^ ((row & 7) << 4))) =
            (__bf16)fast_tanh(C[r]);
      }
    }
    __syncthreads();  // bar1

    // ---------------- phase B: L2 (4 tiles x 16 steps, B-ring 8) ----------
    kcur[tid] = 0.f;
    kcur[tid + 512] = 0.f;
    {
      const __bf16* wbase = W2P + lq * 4096 + (w * 64 + lr) * 8;
      bfv8 Bb[8];
#pragma unroll
      for (int u = 0; u < 8; ++u)
        Bb[u] = *(const bfv8*)(wbase + (u & 15) * 16384 + (u >> 4) * 128);
      bfv8 A[16];
#pragma unroll
      for (int c = 0; c < 16; ++c)
        A[c] = *(const bfv8*)(h1c + lr * 1024 +
                              (((c * 64) + lq * 16) ^ ((lr & 7) << 4)));
      f32x4 Ca = splat4(0.f), Cb = splat4(0.f);
#pragma unroll
      for (int u = 0; u < 64; ++u) {
        const int c = u & 15, n = u >> 4;
        if (c == 0) { Ca = splat4(0.f); Cb = splat4(0.f); }
        if (u & 1)
          Cb = __builtin_amdgcn_mfma_f32_16x16x32_bf16(A[c], Bb[u & 7], Cb, 0, 0, 0);
        else
          Ca = __builtin_amdgcn_mfma_f32_16x16x32_bf16(A[c], Bb[u & 7], Ca, 0, 0, 0);
        if (u + 8 < 64)
          Bb[u & 7] = *(const bfv8*)(wbase + ((u + 8) & 15) * 16384 +
                                     ((u + 8) >> 4) * 128);
        if (c == 15) {
#pragma unroll
          for (int r = 0; r < 4; ++r) {
            const int row = lq * 4 + r;
            const int col = w * 64 + n * 16 + lr;
            const float tv = fast_tanh(Ca[r] + Cb[r] + b2c[n]);
            const int boff = row * 1024 + ((col * 2) ^ ((row & 7) << 4));
            *(__bf16*)((char*)h2s + boff) = (__bf16)tv;
            *(__bf16*)((char*)vs + boff) = (__bf16)(1.f - tv * tv);
          }
        }
      }
    }
    __syncthreads();  // bar2

    // ------- phase C: 72 chunks (64 TR-halves + 8 L3-halves), 9/wave -------
    {
      bfv8 Ab[2][8], Bc[2][8];
      pref_chunk(w * 9, lr, lq, GtP, W3P, vsc, h2c, Ab[0], Bc[0]);
#pragma unroll
      for (int i = 0; i < 9; ++i) {
        const int id = w * 9 + i;
        const bool isTR = id < 64;
        const int tl = (isTR ? id : id - 64) >> 1;
        if (i < 8)
          pref_chunk(id + 1, lr, lq, GtP, W3P, vsc, h2c, Ab[(i + 1) & 1],
                     Bc[(i + 1) & 1]);
        f32x4 C = splat4((!isTR && (id & 1) == 0) ? b3c[tl] : 0.f);
#pragma unroll
        for (int c = 0; c < 8; ++c)
          C = __builtin_amdgcn_mfma_f32_16x16x32_bf16(Ab[i & 1][c], Bc[i & 1][c],
                                                      C, 0, 0, 0);
        if (isTR) {
#pragma unroll
          for (int r = 0; r < 4; ++r) {
            const int row = lq * 4 + r;
            const int col = tl * 16 + lr;
            const float h1v = (float)*(const __bf16*)(
                h1c + row * 1024 + ((col * 2) ^ ((row & 7) << 4)));
            float p = C[r] * (1.f - h1v * h1v);
            p += __shfl_xor(p, 1);
            p += __shfl_xor(p, 2);
            p += __shfl_xor(p, 4);
            p += __shfl_xor(p, 8);
            if (lr == 0) atomicAdd(&trbuf[row], p);
          }
        } else {
#pragma unroll
          for (int r = 0; r < 4; ++r)
            atomicAdd(&kcur[(lq * 4 + r) * 64 + tl * 16 + lr], C[r]);
        }
      }
    }
    __syncthreads();  // bar3
  }

  // epilogue: final state -> out
  if (w == 0) {
    float* orow = out + (rowbase + lr) * 64 + lq * 8;
#pragma unroll
    for (int e = 0; e < 8; ++e) { orow[e] = xb0[e]; orow[32 + e] = xb1[e]; }
  }
  if (w == 7 && lq == 0) out[512 * 64 + rowbase + lr] = ldv;
}

extern "C" void kernel_launch(void* const* d_in, const int* in_sizes, int n_in,
                              void* d_out, int out_size, void* d_ws,
                              size_t ws_size, hipStream_t stream) {
  const float* x = (const float*)d_in[0];
  const float* W1 = (const float*)d_in[1];
  const float* b1 = (const float*)d_in[2];
  const float* W2 = (const float*)d_in[3];
  const float* b2 = (const float*)d_in[4];
  const float* W3 = (const float*)d_in[5];
  const float* b3 = (const float*)d_in[6];
  float* out = (float*)d_out;
  __bf16* wsb = (__bf16*)d_ws;

  __bf16* W1P = wsb;            // 32768
  __bf16* W2P = wsb + 32768;    // 262144
  __bf16* GtP = wsb + 294912;   // 262144
  __bf16* W3P = wsb + 557056;   // 32768

  pre_kernel<<<288, 256, 0, stream>>>(W1, W2, W3, W1P, W2P, GtP, W3P);
  cnf_kernel<<<32, 512, 0, stream>>>(x, W1, b1, b2, b3, W1P, W2P, GtP, W3P,
                                     out);
}